// Round 18
// baseline (146.697 us; speedup 1.0000x reference)
//
#include <hip/hip_runtime.h>
#include <stdint.h>

typedef unsigned long long u64;
typedef uint32_t u32;

#define BB  32
#define CC  256
#define HH  56
#define WW  56
#define OHH 28
#define OWW 28
#define NPIX (BB*OHH*OWW)   // 25088
#define PACKBLKS 3136       // 802816/256

// ---------------- Kernel 0: pack sign(x+beta1)+avgpool (blocks 0..3135)
//                  + weight prep/alpha/stats-zero (blocks 3136..3647, runs concurrently) ----
__global__ __launch_bounds__(256) void rrb_prep_pack(const float* __restrict__ x,
                                                     const float* __restrict__ rsb1,
                                                     const float* __restrict__ w1,
                                                     const float* __restrict__ w2,
                                                     u32* __restrict__ xb, float* __restrict__ pool,
                                                     u32* __restrict__ wp1, u32* __restrict__ wp2,
                                                     float* __restrict__ alpha1, float* __restrict__ alpha2,
                                                     u32* __restrict__ stats_zero) {
    if (blockIdx.x >= PACKBLKS) {
        // ---- weight prep path ----
        __shared__ float red[256];
        int pb = blockIdx.x - PACKBLKS;     // 0..511
        int co = pb & 255;
        int t = threadIdx.x;                // ci
        int wid = t >> 6, lane = t & 63;
        if (pb == 0) {
            #pragma unroll
            for (int k = 0; k < 6; ++k) stats_zero[k * 256 + t] = 0u;
        }
        float asum = 0.f;
        if (pb < 256) {
            const float* wr = w1 + (size_t)co * 2304 + (size_t)t * 9;
            float v[9];
            #pragma unroll
            for (int k = 0; k < 9; ++k) { v[k] = wr[k]; asum += fabsf(v[k]); }
            #pragma unroll
            for (int k = 0; k < 9; ++k) {
                u64 m = __ballot(v[k] > 0.f);
                if (lane == 0)
                    *(u64*)&wp1[((size_t)co * 9 + k) * 8 + 2 * wid] = m;
            }
        } else {
            float v = w2[co * 256 + t];
            asum = fabsf(v);
            u64 m = __ballot(v > 0.f);
            if (lane == 0) *(u64*)&wp2[co * 8 + 2 * wid] = m;
        }
        red[t] = asum; __syncthreads();
        for (int st = 128; st > 0; st >>= 1) {
            if (t < st) red[t] += red[t + st];
            __syncthreads();
        }
        if (t == 0) {
            if (pb < 256) alpha1[co] = red[0] / 2304.f;
            else          alpha2[co] = red[0] / 256.f;
        }
        return;
    }
    // ---- pack path: thread = (j-word, n, oh, ow, s-subslice) ----
    int i = blockIdx.x * 256 + threadIdx.x;   // 802816
    int s  = i & 3;
    int i2 = i >> 2;
    int ow = i2 % OWW;
    int i3 = i2 / OWW;
    int oh = i3 % OHH;
    int i4 = i3 / OHH;
    int n  = i4 & 31;
    int j  = i4 >> 5;
    int c0 = 32 * j + 8 * s;
    const float* base = x + (((size_t)(n * CC + c0) * HH + 2 * oh) * WW + 2 * ow);

    float2 a0[8], a1[8];
    #pragma unroll
    for (int cc = 0; cc < 8; ++cc) {
        const float* p = base + (size_t)cc * (HH * WW);
        a0[cc] = *(const float2*)p;
        a1[cc] = *(const float2*)(p + WW);
    }
    float4 b0 = *(const float4*)&rsb1[c0];
    float4 b1 = *(const float4*)&rsb1[c0 + 4];

    u32 w00 = 0, w01 = 0, w10 = 0, w11 = 0;
    float pv[8];
    #pragma unroll
    for (int cc = 0; cc < 8; ++cc) {
        float b = (cc < 4) ? ((const float*)&b0)[cc] : ((const float*)&b1)[cc - 4];
        w00 |= (u32)(a0[cc].x + b > 0.f) << cc;
        w01 |= (u32)(a0[cc].y + b > 0.f) << cc;
        w10 |= (u32)(a1[cc].x + b > 0.f) << cc;
        w11 |= (u32)(a1[cc].y + b > 0.f) << cc;
        pv[cc] = (a0[cc].x + a0[cc].y + a1[cc].x + a1[cc].y) * 0.25f;
    }
    w00 <<= 8 * s; w01 <<= 8 * s; w10 <<= 8 * s; w11 <<= 8 * s;
    w00 |= __shfl_xor(w00, 1); w00 |= __shfl_xor(w00, 2);
    w01 |= __shfl_xor(w01, 1); w01 |= __shfl_xor(w01, 2);
    w10 |= __shfl_xor(w10, 1); w10 |= __shfl_xor(w10, 2);
    w11 |= __shfl_xor(w11, 1); w11 |= __shfl_xor(w11, 2);

    float* pp = pool + ((size_t)(n * OHH + oh) * OWW + ow) * CC + c0;
    *(float4*)&pp[0] = make_float4(pv[0], pv[1], pv[2], pv[3]);
    *(float4*)&pp[4] = make_float4(pv[4], pv[5], pv[6], pv[7]);

    u32* xo = xb + (((size_t)(n * HH + 2 * oh) * WW + 2 * ow) * 8) + j;
    u32 wsel = (s == 0) ? w00 : (s == 1) ? w01 : (s == 2) ? w10 : w11;
    int off = (s == 0) ? 0 : (s == 1) ? 8 : (s == 2) ? WW * 8 : WW * 8 + 8;
    xo[off] = wsel;
}

// ---------------- Kernel 1: binary conv1 (3x3,s2,p1), lane-pair SPLIT-K ----------
// 512 threads: c = t>>1 (co), h = t&1 (word half, 4h..4h+3). K-halves sit in ADJACENT
// LANES -> combine via __shfl_xor(Q,1) (quad-perm DPP, ~1cy). No qh LDS, no extra
// barrier, no idle half in the tail. Exact same integers as R13/R17.
__global__ __launch_bounds__(512) void rrb_conv1(const u32* __restrict__ xb,
                                                 const u32* __restrict__ wp1,
                                                 short* __restrict__ S1,
                                                 int* __restrict__ s_sum, u64* __restrict__ s_sq) {
    __shared__ u32 xs[3 * WW * 8];          // 5376 B only
    int blk = blockIdx.x;
    int n = blk / OHH, oh = blk - n * OHH;
    int t = threadIdx.x;
    int c = t >> 1;
    int h = t & 1;
    int r0 = 2 * oh - 1;
    for (int i = t; i < 3 * WW * 8; i += 512) {
        int row = i / (WW * 8);
        int ih = r0 + row;
        xs[i] = (ih >= 0) ? xb[((size_t)(n * HH + ih) * WW) * 8 + (i - row * WW * 8)] : 0u;
    }
    u32 wreg[36];
    {
        const u32* wsrc = wp1 + (size_t)c * 72 + 4 * h;
        #pragma unroll
        for (int k = 0; k < 9; ++k) {
            wreg[4 * k + 0] = wsrc[8 * k + 0];
            wreg[4 * k + 1] = wsrc[8 * k + 1];
            wreg[4 * k + 2] = wsrc[8 * k + 2];
            wreg[4 * k + 3] = wsrc[8 * k + 3];
        }
    }
    __syncthreads();
    bool oh0 = (oh == 0);
    int rv = oh0 ? 2 : 3;
    int bsum = 0; long long bsq = 0;
    short* outp = S1 + ((size_t)(n * OHH + oh) * OWW) * CC + c;
    #pragma unroll
    for (int ow = 0; ow < OWW; ++ow) {
        int Q = 0;
        #pragma unroll
        for (int kh = 0; kh < 3; ++kh) {
            bool vkh = !(kh == 0 && oh0);
            #pragma unroll
            for (int kw = 0; kw < 3; ++kw) {
                int iw = 2 * ow + kw - 1;
                bool ok = vkh && (iw >= 0);
                int iwc = iw < 0 ? 0 : iw;
                const u32* xp = &xs[(kh * WW + iwc) * 8 + 4 * h];
                int p = 0;
                #pragma unroll
                for (int j = 0; j < 4; ++j) p += __popc(xp[j] ^ wreg[(kh * 3 + kw) * 4 + j]);
                Q += ok ? p : 0;
            }
        }
        Q += __shfl_xor(Q, 1);          // lane-pair combine: both lanes hold Q0+Q1
        int V = rv * (ow == 0 ? 2 : 3);
        int S = 256 * V - 2 * Q;
        if (h == 0) outp[ow * CC] = (short)S;
        bsum += S;
        bsq += (long long)S * S;
    }
    if (h == 0) {
        atomicAdd(&s_sum[c], bsum);
        atomicAdd(&s_sq[c], (u64)bsq);
    }
}

// ---- BN finalize (exact integer stats -> A,B), inlined into consumers ----
__device__ __forceinline__ void bn_fold(const int* ssum, const u64* ssq,
                                        const float* alpha, const float* gamma,
                                        const float* beta, int c, float& a, float& b) {
    const double N = (double)NPIX;
    double s = (double)ssum[c];
    double q = (double)ssq[c];
    double mS = s / N;
    double vS = q / N - mS * mS;
    double al = (double)alpha[c];
    double scale = (double)gamma[c] / sqrt(al * al * vS + 1e-5);
    a = (float)(al * scale);
    b = (float)((double)beta[c] - al * mS * scale);
}

// ---------------- Kernel 2: out1 = rprelu(bn1+pool) (in-place) + conv2 bn2-stats ----------
__global__ __launch_bounds__(256) void rrb_out1c2(const short* __restrict__ S1,
                                                  float* __restrict__ pool,
                                                  const int* __restrict__ ssum, const u64* __restrict__ ssq,
                                                  const float* __restrict__ alpha1,
                                                  const float* __restrict__ bn1g, const float* __restrict__ bn1b,
                                                  const float* __restrict__ pg, const float* __restrict__ pz,
                                                  const float* __restrict__ ps, const float* __restrict__ rsb2,
                                                  const u32* __restrict__ wp2,
                                                  int* __restrict__ s_sum2, u64* __restrict__ s_sq2) {
    __shared__ u32 xsb[14 * 8];      // 448 B of sign bits
    int blk = blockIdx.x;
    int half = blk & 1;
    int rest = blk >> 1;
    int n = rest / OHH, oh = rest - n * OHH;
    int owlo = half * 14;
    int c = threadIdx.x;
    int wid = c >> 6, lane = c & 63;
    float a, b;
    bn_fold(ssum, ssq, alpha1, bn1g, bn1b, c, a, b);
    float g = pg[c], z = pz[c], s = ps[c], b2 = rsb2[c];
    size_t pixbase = ((size_t)(n * OHH + oh) * OWW + owlo);
    const short* sp = S1 + pixbase * CC + c;
    float* pp = pool + pixbase * CC + c;
    float sv[14], pv[14];
    #pragma unroll
    for (int k = 0; k < 14; ++k) sv[k] = (float)sp[k * CC];
    #pragma unroll
    for (int k = 0; k < 14; ++k) pv[k] = pp[k * CC];
    #pragma unroll
    for (int k = 0; k < 14; ++k) {
        float v = a * sv[k] + b + pv[k];
        float xsv = v - g;
        float o = (xsv > 0.f ? xsv : s * xsv) + z;
        pp[k * CC] = o;
        u64 m = __ballot(o + b2 > 0.f);
        if (lane == 0) *(u64*)&xsb[k * 8 + 2 * wid] = m;
    }
    __syncthreads();
    u32 wr[8];
    {
        const u32* wsv = wp2 + (size_t)c * 8;
        #pragma unroll
        for (int j = 0; j < 8; ++j) wr[j] = wsv[j];
    }
    int bsum = 0; long long bsq = 0;
    #pragma unroll
    for (int k = 0; k < 14; ++k) {
        int p = 0;
        #pragma unroll
        for (int j = 0; j < 8; ++j) p += __popc(xsb[k * 8 + j] ^ wr[j]);
        int S = 256 - 2 * p;
        bsum += S;
        bsq += (long long)S * S;
    }
    atomicAdd(&s_sum2[c], bsum);
    atomicAdd(&s_sq2[c], (u64)bsq);
}

// ---------------- Kernel 3: recompute conv2 from out1, y = bn2 + out1, concat ----------
__global__ __launch_bounds__(256) void rrb_final(const float* __restrict__ out1,
                                                 const int* __restrict__ ssum, const u64* __restrict__ ssq,
                                                 const float* __restrict__ alpha2,
                                                 const float* __restrict__ bn2g, const float* __restrict__ bn2b,
                                                 const float* __restrict__ rsb2,
                                                 const u32* __restrict__ wp2,
                                                 float* __restrict__ y) {
    __shared__ u32 bits[OWW * 8];    // 896 B
    __shared__ float lds[256 * 29];  // 29.7 KB transpose buffer (pad 29)
    int blk = blockIdx.x;
    int n = blk / OHH, oh = blk - n * OHH;
    int c = threadIdx.x;
    int wid = c >> 6, lane = c & 63;
    float a, b;
    bn_fold(ssum, ssq, alpha2, bn2g, bn2b, c, a, b);
    float b2 = rsb2[c];
    size_t pixbase = ((size_t)(n * OHH + oh) * OWW);
    const float* op = out1 + pixbase * CC + c;
    float ov[OWW];
    #pragma unroll
    for (int ow = 0; ow < OWW; ++ow) ov[ow] = op[ow * CC];
    #pragma unroll
    for (int ow = 0; ow < OWW; ++ow) {
        u64 m = __ballot(ov[ow] + b2 > 0.f);
        if (lane == 0) *(u64*)&bits[ow * 8 + 2 * wid] = m;
    }
    u32 wr[8];
    {
        const u32* wsv = wp2 + (size_t)c * 8;
        #pragma unroll
        for (int j = 0; j < 8; ++j) wr[j] = wsv[j];
    }
    __syncthreads();
    #pragma unroll
    for (int ow = 0; ow < OWW; ++ow) {
        int p = 0;
        #pragma unroll
        for (int j = 0; j < 8; ++j) p += __popc(bits[ow * 8 + j] ^ wr[j]);
        int S = 256 - 2 * p;
        lds[c * 29 + ow] = a * (float)S + b + ov[ow];
    }
    __syncthreads();
    #pragma unroll
    for (int it = 0; it < 7; ++it) {
        int idx = it * 256 + c;        // 0..1791 = 256 rows x 7 float4
        int cp = idx / 7, qq = idx - cp * 7;
        const float* lp = &lds[cp * 29 + 4 * qq];
        float4 v = make_float4(lp[0], lp[1], lp[2], lp[3]);
        float* dst = y + ((size_t)(n * 2 * CC + cp) * OHH + oh) * OWW + 4 * qq;
        *(float4*)dst = v;
        *(float4*)(dst + (size_t)CC * OHH * OWW) = v;
    }
}

extern "C" void kernel_launch(void* const* d_in, const int* in_sizes, int n_in,
                              void* d_out, int out_size, void* d_ws, size_t ws_size,
                              hipStream_t stream) {
    const float* x    = (const float*)d_in[0];
    const float* rsb1 = (const float*)d_in[1];
    const float* w1   = (const float*)d_in[2];
    const float* bn1g = (const float*)d_in[3];
    const float* bn1b = (const float*)d_in[4];
    const float* rsb2 = (const float*)d_in[5];
    const float* w2   = (const float*)d_in[6];
    const float* bn2g = (const float*)d_in[7];
    const float* bn2b = (const float*)d_in[8];
    const float* pg   = (const float*)d_in[9];
    const float* pz   = (const float*)d_in[10];
    const float* ps   = (const float*)d_in[11];
    float* y = (float*)d_out;

    char* ws = (char*)d_ws;
    if (ws_size < 41840640) return;

    u32*   wp1    = (u32*)(ws + 0);          // 73728 B
    u32*   wp2    = (u32*)(ws + 73728);      // 8192 B
    float* alpha1 = (float*)(ws + 81920);
    float* alpha2 = (float*)(ws + 82944);
    int*   st1_sum = (int*)(ws + 88064);     // 1024 B
    u64*   st1_sq  = (u64*)(ws + 89088);     // 2048 B
    int*   st2_sum = (int*)(ws + 91136);     // 1024 B
    u64*   st2_sq  = (u64*)(ws + 92160);     // 2048 B  (stats: 6144 B @88064)
    u32*   xb   = (u32*)(ws + 94208);        // 3,211,264 B   [n][h][w][8]
    float* pool = (float*)(ws + 3305472);    // 25,690,112 B  [pix][256] (becomes out1)
    short* S1   = (short*)(ws + 28995584);   // 12,845,056 B  [pix][256] -> end 41,840,640

    rrb_prep_pack<<<PACKBLKS + 512, 256, 0, stream>>>(x, rsb1, w1, w2, xb, pool,
                                                      wp1, wp2, alpha1, alpha2,
                                                      (u32*)(ws + 88064));
    rrb_conv1<<<BB * OHH, 512, 0, stream>>>(xb, wp1, S1, st1_sum, st1_sq);
    rrb_out1c2<<<BB * OHH * 2, 256, 0, stream>>>(S1, pool, st1_sum, st1_sq, alpha1,
                                                 bn1g, bn1b, pg, pz, ps, rsb2,
                                                 wp2, st2_sum, st2_sq);
    rrb_final<<<BB * OHH, 256, 0, stream>>>(pool, st2_sum, st2_sq, alpha2,
                                            bn2g, bn2b, rsb2, wp2, y);
}

// Round 19
// 143.283 us; speedup vs baseline: 1.0238x; 1.0238x over previous
//
#include <hip/hip_runtime.h>
#include <stdint.h>

typedef unsigned long long u64;
typedef uint32_t u32;

#define BB  32
#define CC  256
#define HH  56
#define WW  56
#define OHH 28
#define OWW 28
#define NPIX (BB*OHH*OWW)   // 25088
#define PACKBLKS 3136       // 802816/256

// ---------------- Kernel 0: pack sign(x+beta1)+avgpool (blocks 0..3135)
//                  + weight prep/alpha/stats-zero (blocks 3136..3647, runs concurrently) ----
__global__ __launch_bounds__(256) void rrb_prep_pack(const float* __restrict__ x,
                                                     const float* __restrict__ rsb1,
                                                     const float* __restrict__ w1,
                                                     const float* __restrict__ w2,
                                                     u32* __restrict__ xb, float* __restrict__ pool,
                                                     u32* __restrict__ wp1, u32* __restrict__ wp2,
                                                     float* __restrict__ alpha1, float* __restrict__ alpha2,
                                                     u32* __restrict__ stats_zero) {
    if (blockIdx.x >= PACKBLKS) {
        // ---- weight prep path ----
        __shared__ float red[256];
        int pb = blockIdx.x - PACKBLKS;     // 0..511
        int co = pb & 255;
        int t = threadIdx.x;                // ci
        int wid = t >> 6, lane = t & 63;
        if (pb == 0) {
            #pragma unroll
            for (int k = 0; k < 6; ++k) stats_zero[k * 256 + t] = 0u;
        }
        float asum = 0.f;
        if (pb < 256) {
            const float* wr = w1 + (size_t)co * 2304 + (size_t)t * 9;
            float v[9];
            #pragma unroll
            for (int k = 0; k < 9; ++k) { v[k] = wr[k]; asum += fabsf(v[k]); }
            #pragma unroll
            for (int k = 0; k < 9; ++k) {
                u64 m = __ballot(v[k] > 0.f);
                if (lane == 0)
                    *(u64*)&wp1[((size_t)co * 9 + k) * 8 + 2 * wid] = m;
            }
        } else {
            float v = w2[co * 256 + t];
            asum = fabsf(v);
            u64 m = __ballot(v > 0.f);
            if (lane == 0) *(u64*)&wp2[co * 8 + 2 * wid] = m;
        }
        red[t] = asum; __syncthreads();
        for (int st = 128; st > 0; st >>= 1) {
            if (t < st) red[t] += red[t + st];
            __syncthreads();
        }
        if (t == 0) {
            if (pb < 256) alpha1[co] = red[0] / 2304.f;
            else          alpha2[co] = red[0] / 256.f;
        }
        return;
    }
    // ---- pack path: thread = (j-word, n, oh, ow, s-subslice) ----
    int i = blockIdx.x * 256 + threadIdx.x;   // 802816
    int s  = i & 3;
    int i2 = i >> 2;
    int ow = i2 % OWW;
    int i3 = i2 / OWW;
    int oh = i3 % OHH;
    int i4 = i3 / OHH;
    int n  = i4 & 31;
    int j  = i4 >> 5;
    int c0 = 32 * j + 8 * s;
    const float* base = x + (((size_t)(n * CC + c0) * HH + 2 * oh) * WW + 2 * ow);

    float2 a0[8], a1[8];
    #pragma unroll
    for (int cc = 0; cc < 8; ++cc) {
        const float* p = base + (size_t)cc * (HH * WW);
        a0[cc] = *(const float2*)p;
        a1[cc] = *(const float2*)(p + WW);
    }
    float4 b0 = *(const float4*)&rsb1[c0];
    float4 b1 = *(const float4*)&rsb1[c0 + 4];

    u32 w00 = 0, w01 = 0, w10 = 0, w11 = 0;
    float pv[8];
    #pragma unroll
    for (int cc = 0; cc < 8; ++cc) {
        float b = (cc < 4) ? ((const float*)&b0)[cc] : ((const float*)&b1)[cc - 4];
        w00 |= (u32)(a0[cc].x + b > 0.f) << cc;
        w01 |= (u32)(a0[cc].y + b > 0.f) << cc;
        w10 |= (u32)(a1[cc].x + b > 0.f) << cc;
        w11 |= (u32)(a1[cc].y + b > 0.f) << cc;
        pv[cc] = (a0[cc].x + a0[cc].y + a1[cc].x + a1[cc].y) * 0.25f;
    }
    w00 <<= 8 * s; w01 <<= 8 * s; w10 <<= 8 * s; w11 <<= 8 * s;
    w00 |= __shfl_xor(w00, 1); w00 |= __shfl_xor(w00, 2);
    w01 |= __shfl_xor(w01, 1); w01 |= __shfl_xor(w01, 2);
    w10 |= __shfl_xor(w10, 1); w10 |= __shfl_xor(w10, 2);
    w11 |= __shfl_xor(w11, 1); w11 |= __shfl_xor(w11, 2);

    float* pp = pool + ((size_t)(n * OHH + oh) * OWW + ow) * CC + c0;
    *(float4*)&pp[0] = make_float4(pv[0], pv[1], pv[2], pv[3]);
    *(float4*)&pp[4] = make_float4(pv[4], pv[5], pv[6], pv[7]);

    u32* xo = xb + (((size_t)(n * HH + 2 * oh) * WW + 2 * ow) * 8) + j;
    u32 wsel = (s == 0) ? w00 : (s == 1) ? w01 : (s == 2) ? w10 : w11;
    int off = (s == 0) ? 0 : (s == 1) ? 8 : (s == 2) ? WW * 8 : WW * 8 + 8;
    xo[off] = wsel;
}

// ---------------- Kernel 1: binary conv1 (3x3,s2,p1), SPLIT-K + bn1 atomic stats ----------
// R13/R17 conv1 exactly (512 thr, 36 wreg, qh combine, h=0 tail) — best of 6 variants.
__global__ __launch_bounds__(512) void rrb_conv1(const u32* __restrict__ xb,
                                                 const u32* __restrict__ wp1,
                                                 short* __restrict__ S1,
                                                 int* __restrict__ s_sum, u64* __restrict__ s_sq) {
    __shared__ u32 xs[3 * WW * 8];          // 5376 B
    __shared__ ushort qh[OWW][2][256];      // 28672 B
    int blk = blockIdx.x;
    int n = blk / OHH, oh = blk - n * OHH;
    int t = threadIdx.x;
    int c = t & 255;
    int h = t >> 8;
    int r0 = 2 * oh - 1;
    for (int i = t; i < 3 * WW * 8; i += 512) {
        int row = i / (WW * 8);
        int ih = r0 + row;
        xs[i] = (ih >= 0) ? xb[((size_t)(n * HH + ih) * WW) * 8 + (i - row * WW * 8)] : 0u;
    }
    u32 wreg[36];
    {
        const u32* wsrc = wp1 + (size_t)c * 72 + 4 * h;
        #pragma unroll
        for (int k = 0; k < 9; ++k) {
            wreg[4 * k + 0] = wsrc[8 * k + 0];
            wreg[4 * k + 1] = wsrc[8 * k + 1];
            wreg[4 * k + 2] = wsrc[8 * k + 2];
            wreg[4 * k + 3] = wsrc[8 * k + 3];
        }
    }
    __syncthreads();
    bool oh0 = (oh == 0);
    #pragma unroll
    for (int ow = 0; ow < OWW; ++ow) {
        int Q = 0;
        #pragma unroll
        for (int kh = 0; kh < 3; ++kh) {
            bool vkh = !(kh == 0 && oh0);
            #pragma unroll
            for (int kw = 0; kw < 3; ++kw) {
                int iw = 2 * ow + kw - 1;
                bool ok = vkh && (iw >= 0);
                int iwc = iw < 0 ? 0 : iw;
                const u32* xp = &xs[(kh * WW + iwc) * 8 + 4 * h];
                int p = 0;
                #pragma unroll
                for (int j = 0; j < 4; ++j) p += __popc(xp[j] ^ wreg[(kh * 3 + kw) * 4 + j]);
                Q += ok ? p : 0;
            }
        }
        qh[ow][h][c] = (ushort)Q;
    }
    __syncthreads();
    if (h == 0) {
        int rv = oh0 ? 2 : 3;
        int bsum = 0; long long bsq = 0;
        short* outp = S1 + ((size_t)(n * OHH + oh) * OWW) * CC + c;
        #pragma unroll
        for (int ow = 0; ow < OWW; ++ow) {
            int V = rv * (ow == 0 ? 2 : 3);
            int S = 256 * V - 2 * ((int)qh[ow][0][c] + (int)qh[ow][1][c]);
            outp[ow * CC] = (short)S;
            bsum += S;
            bsq += (long long)S * S;
        }
        atomicAdd(&s_sum[c], bsum);
        atomicAdd(&s_sq[c], (u64)bsq);
    }
}

// ---- BN finalize (exact integer stats -> A,B), inlined into consumers ----
__device__ __forceinline__ void bn_fold(const int* ssum, const u64* ssq,
                                        const float* alpha, const float* gamma,
                                        const float* beta, int c, float& a, float& b) {
    const double N = (double)NPIX;
    double s = (double)ssum[c];
    double q = (double)ssq[c];
    double mS = s / N;
    double vS = q / N - mS * mS;
    double al = (double)alpha[c];
    double scale = (double)gamma[c] / sqrt(al * al * vS + 1e-5);
    a = (float)(al * scale);
    b = (float)((double)beta[c] - al * mS * scale);
}

// ---------------- Kernel 2: out1 = rprelu(bn1+pool) (in-place) + conv2 bn2-stats ----------
__global__ __launch_bounds__(256) void rrb_out1c2(const short* __restrict__ S1,
                                                  float* __restrict__ pool,
                                                  const int* __restrict__ ssum, const u64* __restrict__ ssq,
                                                  const float* __restrict__ alpha1,
                                                  const float* __restrict__ bn1g, const float* __restrict__ bn1b,
                                                  const float* __restrict__ pg, const float* __restrict__ pz,
                                                  const float* __restrict__ ps, const float* __restrict__ rsb2,
                                                  const u32* __restrict__ wp2,
                                                  int* __restrict__ s_sum2, u64* __restrict__ s_sq2) {
    __shared__ u32 xsb[14 * 8];      // 448 B of sign bits
    int blk = blockIdx.x;
    int half = blk & 1;
    int rest = blk >> 1;
    int n = rest / OHH, oh = rest - n * OHH;
    int owlo = half * 14;
    int c = threadIdx.x;
    int wid = c >> 6, lane = c & 63;
    float a, b;
    bn_fold(ssum, ssq, alpha1, bn1g, bn1b, c, a, b);
    float g = pg[c], z = pz[c], s = ps[c], b2 = rsb2[c];
    size_t pixbase = ((size_t)(n * OHH + oh) * OWW + owlo);
    const short* sp = S1 + pixbase * CC + c;
    float* pp = pool + pixbase * CC + c;
    float sv[14], pv[14];
    #pragma unroll
    for (int k = 0; k < 14; ++k) sv[k] = (float)sp[k * CC];
    #pragma unroll
    for (int k = 0; k < 14; ++k) pv[k] = pp[k * CC];
    #pragma unroll
    for (int k = 0; k < 14; ++k) {
        float v = a * sv[k] + b + pv[k];
        float xsv = v - g;
        float o = (xsv > 0.f ? xsv : s * xsv) + z;
        pp[k * CC] = o;
        u64 m = __ballot(o + b2 > 0.f);
        if (lane == 0) *(u64*)&xsb[k * 8 + 2 * wid] = m;
    }
    __syncthreads();
    u32 wr[8];
    {
        const u32* wsv = wp2 + (size_t)c * 8;
        #pragma unroll
        for (int j = 0; j < 8; ++j) wr[j] = wsv[j];
    }
    int bsum = 0; long long bsq = 0;
    #pragma unroll
    for (int k = 0; k < 14; ++k) {
        int p = 0;
        #pragma unroll
        for (int j = 0; j < 8; ++j) p += __popc(xsb[k * 8 + j] ^ wr[j]);
        int S = 256 - 2 * p;
        bsum += S;
        bsq += (long long)S * S;
    }
    atomicAdd(&s_sum2[c], bsum);
    atomicAdd(&s_sq2[c], (u64)bsq);
}

// ---------------- Kernel 3: recompute conv2 from out1, y = bn2 + out1, concat ----------
__global__ __launch_bounds__(256) void rrb_final(const float* __restrict__ out1,
                                                 const int* __restrict__ ssum, const u64* __restrict__ ssq,
                                                 const float* __restrict__ alpha2,
                                                 const float* __restrict__ bn2g, const float* __restrict__ bn2b,
                                                 const float* __restrict__ rsb2,
                                                 const u32* __restrict__ wp2,
                                                 float* __restrict__ y) {
    __shared__ u32 bits[OWW * 8];    // 896 B
    __shared__ float lds[256 * 29];  // 29.7 KB transpose buffer (pad 29)
    int blk = blockIdx.x;
    int n = blk / OHH, oh = blk - n * OHH;
    int c = threadIdx.x;
    int wid = c >> 6, lane = c & 63;
    float a, b;
    bn_fold(ssum, ssq, alpha2, bn2g, bn2b, c, a, b);
    float b2 = rsb2[c];
    size_t pixbase = ((size_t)(n * OHH + oh) * OWW);
    const float* op = out1 + pixbase * CC + c;
    float ov[OWW];
    #pragma unroll
    for (int ow = 0; ow < OWW; ++ow) ov[ow] = op[ow * CC];
    #pragma unroll
    for (int ow = 0; ow < OWW; ++ow) {
        u64 m = __ballot(ov[ow] + b2 > 0.f);
        if (lane == 0) *(u64*)&bits[ow * 8 + 2 * wid] = m;
    }
    u32 wr[8];
    {
        const u32* wsv = wp2 + (size_t)c * 8;
        #pragma unroll
        for (int j = 0; j < 8; ++j) wr[j] = wsv[j];
    }
    __syncthreads();
    #pragma unroll
    for (int ow = 0; ow < OWW; ++ow) {
        int p = 0;
        #pragma unroll
        for (int j = 0; j < 8; ++j) p += __popc(bits[ow * 8 + j] ^ wr[j]);
        int S = 256 - 2 * p;
        lds[c * 29 + ow] = a * (float)S + b + ov[ow];
    }
    __syncthreads();
    #pragma unroll
    for (int it = 0; it < 7; ++it) {
        int idx = it * 256 + c;        // 0..1791 = 256 rows x 7 float4
        int cp = idx / 7, qq = idx - cp * 7;
        const float* lp = &lds[cp * 29 + 4 * qq];
        float4 v = make_float4(lp[0], lp[1], lp[2], lp[3]);
        float* dst = y + ((size_t)(n * 2 * CC + cp) * OHH + oh) * OWW + 4 * qq;
        *(float4*)dst = v;
        *(float4*)(dst + (size_t)CC * OHH * OWW) = v;
    }
}

extern "C" void kernel_launch(void* const* d_in, const int* in_sizes, int n_in,
                              void* d_out, int out_size, void* d_ws, size_t ws_size,
                              hipStream_t stream) {
    const float* x    = (const float*)d_in[0];
    const float* rsb1 = (const float*)d_in[1];
    const float* w1   = (const float*)d_in[2];
    const float* bn1g = (const float*)d_in[3];
    const float* bn1b = (const float*)d_in[4];
    const float* rsb2 = (const float*)d_in[5];
    const float* w2   = (const float*)d_in[6];
    const float* bn2g = (const float*)d_in[7];
    const float* bn2b = (const float*)d_in[8];
    const float* pg   = (const float*)d_in[9];
    const float* pz   = (const float*)d_in[10];
    const float* ps   = (const float*)d_in[11];
    float* y = (float*)d_out;

    char* ws = (char*)d_ws;
    if (ws_size < 41840640) return;

    u32*   wp1    = (u32*)(ws + 0);          // 73728 B
    u32*   wp2    = (u32*)(ws + 73728);      // 8192 B
    float* alpha1 = (float*)(ws + 81920);
    float* alpha2 = (float*)(ws + 82944);
    int*   st1_sum = (int*)(ws + 88064);     // 1024 B
    u64*   st1_sq  = (u64*)(ws + 89088);     // 2048 B
    int*   st2_sum = (int*)(ws + 91136);     // 1024 B
    u64*   st2_sq  = (u64*)(ws + 92160);     // 2048 B  (stats: 6144 B @88064)
    u32*   xb   = (u32*)(ws + 94208);        // 3,211,264 B   [n][h][w][8]
    float* pool = (float*)(ws + 3305472);    // 25,690,112 B  [pix][256] (becomes out1)
    short* S1   = (short*)(ws + 28995584);   // 12,845,056 B  [pix][256] -> end 41,840,640

    rrb_prep_pack<<<PACKBLKS + 512, 256, 0, stream>>>(x, rsb1, w1, w2, xb, pool,
                                                      wp1, wp2, alpha1, alpha2,
                                                      (u32*)(ws + 88064));
    rrb_conv1<<<BB * OHH, 512, 0, stream>>>(xb, wp1, S1, st1_sum, st1_sq);
    rrb_out1c2<<<BB * OHH * 2, 256, 0, stream>>>(S1, pool, st1_sum, st1_sq, alpha1,
                                                 bn1g, bn1b, pg, pz, ps, rsb2,
                                                 wp2, st2_sum, st2_sq);
    rrb_final<<<BB * OHH, 256, 0, stream>>>(pool, st2_sum, st2_sq, alpha2,
                                            bn2g, bn2b, rsb2, wp2, y);
}